// Round 1
// baseline (1752.784 us; speedup 1.0000x reference)
//
#include <hip/hip_runtime.h>

// RSNEncoder: 8-step GRU (B=32768, D=512) with odd-step linear mix.
// Strategy: bf16 MFMA GEMMs (fp32 accum), gate math fused in epilogue.
//   gates GEMM: A=[x_i | h] (K=1024), W=[Wih|Whh] rows r/z/n -> 4 acc sets
//   mixed GEMM: A=[h_tmp | x_prev], W=[w1|w2]
// h fp32 lives in d_out (fully rewritten by final step); bf16 h double-buffered.

#define BDIM 32768
#define DDIM 512
#define BD (BDIM * DDIM)

typedef short bf16x8 __attribute__((ext_vector_type(8)));
typedef float f32x4 __attribute__((ext_vector_type(4)));
typedef unsigned short u16x8 __attribute__((ext_vector_type(8)));

__device__ __forceinline__ unsigned short f2bf(float f) {
  union { float f; unsigned u; } v; v.f = f;
  return (unsigned short)((v.u + 0x7fffu + ((v.u >> 16) & 1u)) >> 16);  // RNE
}
__device__ __forceinline__ float sigmf(float x) { return 1.0f / (1.0f + __expf(-x)); }
__device__ __forceinline__ float tanhf_(float x) { return 1.0f - 2.0f / (__expf(2.0f * x) + 1.0f); }

// ---- fp32 -> bf16 convert (vectorized, 8 elems/thread) ----
__global__ void cvt_bf16(const float* __restrict__ in, unsigned short* __restrict__ out) {
  const size_t i = ((size_t)blockIdx.x * 256 + threadIdx.x) * 8;
  const float4 a = *(const float4*)(in + i);
  const float4 b = *(const float4*)(in + i + 4);
  u16x8 o;
  o[0] = f2bf(a.x); o[1] = f2bf(a.y); o[2] = f2bf(a.z); o[3] = f2bf(a.w);
  o[4] = f2bf(b.x); o[5] = f2bf(b.y); o[6] = f2bf(b.z); o[7] = f2bf(b.w);
  *(u16x8*)(out + i) = o;
}

// ---- weight prep: Wg[1536][1024] = [Wih | Whh] bf16 ; Wm[512][1024] = [w1 | w2] bf16 ----
__global__ void prep_w(const float* __restrict__ wih, const float* __restrict__ whh,
                       const float* __restrict__ w1, const float* __restrict__ w2,
                       unsigned short* __restrict__ Wg, unsigned short* __restrict__ Wm) {
  const int i = blockIdx.x * 256 + threadIdx.x;
  if (i < 1536 * 1024) {
    const int j = i >> 10, k = i & 1023;
    const float v = (k < 512) ? wih[j * 512 + k] : whh[j * 512 + (k - 512)];
    Wg[i] = f2bf(v);
  } else {
    const int i2 = i - 1536 * 1024;
    const int j = i2 >> 10, k = i2 & 1023;
    const float v = (k < 512) ? w1[j * 512 + k] : w2[j * 512 + (k - 512)];
    Wm[i2] = f2bf(v);
  }
}

// ---- fused step GEMM ----
// NG=3: gates. acc sets: 0=r (all K), 1=z (all K), 2=i_n (K<512), 3=h_n (K>=512).
//       epilogue: r,z,n + h_new = (1-z)*n + z*h_old; writes h fp32 + bf16.
// NG=1: mixed. plain GEMM over K=1024, epilogue writes fp32 + bf16.
// Tile: BM=128, BN=64(d), BK=64. 256 thr = 4 waves (2x2), wave tile 64x32,
// mfma_f32_16x16x32_bf16, fragment layout per learn_hip m89/m97.
template <int NG>
__global__ __launch_bounds__(256, 2) void gemm_step(
    const unsigned short* __restrict__ A0,  // K part 0 (k<512)
    const unsigned short* __restrict__ A1,  // K part 1 (k>=512)
    const unsigned short* __restrict__ W,   // [NG*512][1024] bf16
    const float* __restrict__ bih, const float* __restrict__ bhh,
    const float* hold,                      // fp32 h_old (no restrict: aliases outF)
    float* outF, unsigned short* outB) {
  constexpr int NSET = (NG == 3) ? 4 : 1;
  __shared__ unsigned short sA[128 * 64];
  __shared__ unsigned short sB[NG][64 * 64];

  const int t = threadIdx.x;
  const int lane = t & 63;
  const int wid = t >> 6;
  const int wm = wid >> 1, wn = wid & 1;
  const int bm = blockIdx.x >> 3;
  const int bn = blockIdx.x & 7;

  f32x4 acc[NSET][4][2];
  const f32x4 z4 = {0.f, 0.f, 0.f, 0.f};
#pragma unroll
  for (int s = 0; s < NSET; ++s)
#pragma unroll
    for (int fm = 0; fm < 4; ++fm)
#pragma unroll
      for (int fn = 0; fn < 2; ++fn) acc[s][fm][fn] = z4;

#pragma unroll
  for (int half = 0; half < 2; ++half) {
    const unsigned short* Asrc = half ? A1 : A0;
    const char* ab0 = (const char*)Asrc + (size_t)bm * 128 * 1024;  // row stride 1024 B
    for (int kt8 = 0; kt8 < 8; ++kt8) {
      const int kt = half * 8 + kt8;
      // stage A tile [128][64] bf16 (linear LDS, 16B/lane direct-to-LDS)
#pragma unroll
      for (int j = 0; j < 4; ++j) {
        const int idx = j * 256 + t;
        const char* src = ab0 + (size_t)(idx >> 3) * 1024 + (size_t)(idx & 7) * 16 + (size_t)kt8 * 128;
        __builtin_amdgcn_global_load_lds(
            (const __attribute__((address_space(1))) void*)src,
            (__attribute__((address_space(3))) void*)&sA[idx * 8], 16, 0, 0);
      }
      // stage B tiles [64][64] bf16 per gate (W row stride 2048 B)
#pragma unroll
      for (int g = 0; g < NG; ++g) {
        const char* wb0 = (const char*)W + (size_t)(g * 512 + bn * 64) * 2048 + (size_t)kt * 128;
#pragma unroll
        for (int j = 0; j < 2; ++j) {
          const int idx = j * 256 + t;
          const char* src = wb0 + (size_t)(idx >> 3) * 2048 + (size_t)(idx & 7) * 16;
          __builtin_amdgcn_global_load_lds(
              (const __attribute__((address_space(1))) void*)src,
              (__attribute__((address_space(3))) void*)&sB[g][idx * 8], 16, 0, 0);
        }
      }
      __syncthreads();

#pragma unroll
      for (int ks = 0; ks < 2; ++ks) {
        bf16x8 av[4];
#pragma unroll
        for (int fm = 0; fm < 4; ++fm) {
          const int row = wm * 64 + fm * 16 + (lane & 15);
          av[fm] = *(const bf16x8*)&sA[row * 64 + ks * 32 + (lane >> 4) * 8];
        }
#pragma unroll
        for (int g = 0; g < NG; ++g) {
#pragma unroll
          for (int fn = 0; fn < 2; ++fn) {
            const int rowb = wn * 32 + fn * 16 + (lane & 15);
            const bf16x8 bv = *(const bf16x8*)&sB[g][rowb * 64 + ks * 32 + (lane >> 4) * 8];
            const int set = (NG == 3) ? ((g < 2) ? g : (2 + half)) : 0;  // compile-time (g,half unrolled)
#pragma unroll
            for (int fm = 0; fm < 4; ++fm)
              acc[set][fm][fn] =
                  __builtin_amdgcn_mfma_f32_16x16x32_bf16(av[fm], bv, acc[set][fm][fn], 0, 0, 0);
          }
        }
      }
      __syncthreads();
    }
  }

  // epilogue: C/D map col=lane&15, row=(lane>>4)*4+j  [m89]
  const int erow = (lane >> 4) * 4;
  const int ecol = lane & 15;
  const int r0 = bm * 128 + wm * 64;
  const int c0 = bn * 64 + wn * 32;

#pragma unroll
  for (int fn = 0; fn < 2; ++fn) {
    const int dcol = c0 + fn * 16 + ecol;
    float br = 0.f, bz = 0.f, bi = 0.f, bh = 0.f;
    if constexpr (NG == 3) {
      br = bih[dcol] + bhh[dcol];
      bz = bih[512 + dcol] + bhh[512 + dcol];
      bi = bih[1024 + dcol];
      bh = bhh[1024 + dcol];
    }
#pragma unroll
    for (int fm = 0; fm < 4; ++fm) {
#pragma unroll
      for (int j = 0; j < 4; ++j) {
        const int brow = r0 + fm * 16 + erow + j;
        const size_t off = (size_t)brow * 512 + dcol;
        float hv;
        if constexpr (NG == 3) {
          const float rv = sigmf(acc[0][fm][fn][j] + br);
          const float zv = sigmf(acc[1][fm][fn][j] + bz);
          const float nv = tanhf_(acc[2][fm][fn][j] + bi + rv * (acc[3][fm][fn][j] + bh));
          hv = (1.0f - zv) * nv + zv * hold[off];
        } else {
          hv = acc[0][fm][fn][j];
        }
        outF[off] = hv;
        outB[off] = f2bf(hv);
      }
    }
  }
}

extern "C" void kernel_launch(void* const* d_in, const int* in_sizes, int n_in,
                              void* d_out, int out_size, void* d_ws, size_t ws_size,
                              hipStream_t stream) {
  const float* x   = (const float*)d_in[0];
  const float* wih = (const float*)d_in[1];
  const float* whh = (const float*)d_in[2];
  const float* bih = (const float*)d_in[3];
  const float* bhh = (const float*)d_in[4];
  const float* w1  = (const float*)d_in[5];
  const float* w2  = (const float*)d_in[6];

  // workspace layout (needs ~132 MB)
  char* ws = (char*)d_ws;
  const size_t bd2 = (size_t)BD * 2;
  unsigned short* xb[2] = {(unsigned short*)ws, (unsigned short*)(ws + bd2)};
  unsigned short* hb[2] = {(unsigned short*)(ws + 2 * bd2), (unsigned short*)(ws + 3 * bd2)};
  unsigned short* Wg = (unsigned short*)(ws + 4 * bd2);
  unsigned short* Wm = Wg + 1536 * 1024;
  float* hf = (float*)d_out;  // fp32 h carry; final mixed GEMM rewrites every element

  hipMemsetAsync(hb[0], 0, bd2, stream);               // h0 (bf16) = 0
  hipMemsetAsync(hf, 0, (size_t)BD * 4, stream);       // h0 (fp32) = 0
  prep_w<<<8192, 256, 0, stream>>>(wih, whh, w1, w2, Wg, Wm);

  int hp = 0;
  for (int i = 0; i < 8; ++i) {
    cvt_bf16<<<8192, 256, 0, stream>>>(x + (size_t)i * BD, xb[i & 1]);
    // gates: h_new = GRU(x_i, h); writes hf (fp32) + hb[hp^1] (bf16)
    gemm_step<3><<<2048, 256, 0, stream>>>(xb[i & 1], hb[hp], Wg, bih, bhh, hf, hf, hb[hp ^ 1]);
    hp ^= 1;
    if (i & 1) {
      // mixed = h_tmp @ w1^T + x_{i-1} @ w2^T  (replaces h on odd steps)
      float* of = (i == 7) ? (float*)d_out : hf;
      gemm_step<1><<<2048, 256, 0, stream>>>(hb[hp], xb[(i - 1) & 1], Wm, nullptr, nullptr,
                                             nullptr, of, hb[hp ^ 1]);
      hp ^= 1;
    }
  }
}